// Round 5
// baseline (3395.571 us; speedup 1.0000x reference)
//
#include <hip/hip_runtime.h>
#include <hip/hip_fp16.h>
#include <cstddef>

// StackLSTM: T=64, B=128, H=256, L=2.  ops∈{0,1} => stack never pops:
// top-of-stack = h(last push step), maintained by gated update.
//
// Round-5: L2-streaming with deep MLP. 256 WGs = (q 0..3, bp 0..63); WG owns
// batch elems {2bp, 2bp+1} and gate-col quarter q (256 of 1024 cols/layer,
// h-cols [q*64,(q+1)*64)). Weights f16 [k2][1024], streamed from L2 with
// 16-deep double-buffered load batches. One 4-WG barrier per step, acq/rel
// atomic flags (round-2-proven protocol); flags zeroed via agent-scope atomic
// stores (replay-safe).
#define TT 64
#define BB 128
#define HH 256
#define G4 1024
#define BLK 512

// ws float-slot offsets
#define OFF_XG     0u          // [64 t][64 bp][2 b][4 q][256 lc] fp32 = 8,388,608
#define OFF_WTIH0  8388608u    // [256][1024] fp32 W_ih[0]^T (for xg) = 262,144
#define OFF_PW     8650752u    // 3 x [128 k2][1024 g] uint (f16 pairs) = 393,216
#define OFF_HX0    9043968u    // uint [2 par][64 bp][2 b][128 k2] = 32,768
#define OFF_HX1    9076736u    // same
#define OFF_FLAGS  9109504u    // uint [64 bp][32] = 2048 (one 128B line per bp)
// total 9,111,552 floats = 36.4 MB

__device__ __forceinline__ float sigf(float x) { return 1.0f / (1.0f + expf(-x)); }

typedef _Float16 h2v __attribute__((ext_vector_type(2)));

__device__ __forceinline__ float dot2acc(unsigned w, unsigned h, float acc) {
#if __has_builtin(__builtin_amdgcn_fdot2)
  return __builtin_amdgcn_fdot2(__builtin_bit_cast(h2v, w),
                                __builtin_bit_cast(h2v, h), acc, false);
#else
  __half2 wv = *(__half2*)&w, hv = *(__half2*)&h;
  float2 wf = __half22float2(wv), hf = __half22float2(hv);
  return fmaf(wf.x, hf.x, fmaf(wf.y, hf.y, acc));
#endif
}

// 64 k2-rows of one weight column (stride 1024), dotted with two LDS h vectors.
// 16-deep double-buffered loads -> ~256 B in flight per thread.
__device__ __forceinline__ void dots64(const unsigned* __restrict__ wcol,
                                       const unsigned* __restrict__ hA,
                                       const unsigned* __restrict__ hB,
                                       float& acc0, float& acc1) {
  unsigned w0[16], w1[16];
#pragma unroll
  for (int i = 0; i < 16; ++i) w0[i] = wcol[(size_t)i * 1024];
#pragma unroll
  for (int kk = 0; kk < 4; ++kk) {
    unsigned* cur = (kk & 1) ? w1 : w0;
    unsigned* nxt = (kk & 1) ? w0 : w1;
    if (kk < 3) {
      const unsigned* nw = wcol + (size_t)(kk + 1) * 16 * 1024;
#pragma unroll
      for (int i = 0; i < 16; ++i) nxt[i] = nw[(size_t)i * 1024];
    }
#pragma unroll
    for (int i = 0; i < 16; ++i) {
      acc0 = dot2acc(cur[i], hA[kk * 16 + i], acc0);
      acc1 = dot2acc(cur[i], hB[kk * 16 + i], acc1);
    }
  }
}

// ---------------------------------------------------------------------------
// transpose W_ih[0] [1024][256] -> [256][1024] fp32 (for xg_kernel)
// ---------------------------------------------------------------------------
__global__ void transpose1(const float* __restrict__ W_ih, float* __restrict__ ws) {
  __shared__ float tile[32][33];
  float* dst = ws + OFF_WTIH0;
  const int g0 = blockIdx.x * 32, k0 = blockIdx.y * 32;
  const int tx = threadIdx.x, ty = threadIdx.y;
#pragma unroll
  for (int i = 0; i < 32; i += 8)
    tile[ty + i][tx] = W_ih[(size_t)(g0 + ty + i) * HH + k0 + tx];
  __syncthreads();
#pragma unroll
  for (int i = 0; i < 32; i += 8)
    dst[(size_t)(k0 + ty + i) * G4 + g0 + tx] = tile[tx][ty + i];
}

// ---------------------------------------------------------------------------
// pack W_hh[0], W_ih[1], W_hh[1] as f16 pairs: PW[m][k2][g]
// ---------------------------------------------------------------------------
__global__ void pack_f16(const float* __restrict__ W_ih,
                         const float* __restrict__ W_hh,
                         float* __restrict__ ws) {
  const int fid = blockIdx.x * 256 + threadIdx.x;  // [0, 393216)
  const int m = fid >> 17;
  const int r = fid & 131071;
  const int k2 = r >> 10;
  const int g = r & 1023;
  const float* src = (m == 0) ? W_hh
                   : (m == 1) ? (W_ih + (size_t)G4 * HH)
                              : (W_hh + (size_t)G4 * HH);
  const float* p = src + (size_t)g * HH + k2 * 2;
  const unsigned h0 = __half_as_ushort(__float2half(p[0]));
  const unsigned h1 = __half_as_ushort(__float2half(p[1]));
  ((unsigned*)(ws + OFF_PW))[fid] = h0 | (h1 << 16);
}

// ---------------------------------------------------------------------------
// Xg[t][bp][b][q][lc] = b_ih0[g] + x[t,b,:] @ W_ih0[g,:]   (fp32, exact)
// g = (lc>>6)*256 + q*64 + (lc&63)
// ---------------------------------------------------------------------------
__global__ void xg_kernel(const float* __restrict__ x,
                          const float* __restrict__ b_ih,
                          float* __restrict__ ws) {
  const float* __restrict__ WTih0 = ws + OFF_WTIH0;
  float* __restrict__ Xg = ws + OFF_XG;
  const int r0 = blockIdx.x * 16;
  const int g = blockIdx.y * 256 + threadIdx.x;
  __shared__ float xs[16][HH];
  for (int i = threadIdx.x; i < 16 * HH; i += 256)
    xs[i >> 8][i & 255] = x[(size_t)(r0 + (i >> 8)) * HH + (i & 255)];
  __syncthreads();
  float acc[16];
  const float bias = b_ih[g];
#pragma unroll
  for (int r = 0; r < 16; ++r) acc[r] = bias;
  for (int k = 0; k < HH; ++k) {
    const float w = WTih0[(size_t)k * G4 + g];
#pragma unroll
    for (int r = 0; r < 16; ++r) acc[r] = fmaf(xs[r][k], w, acc[r]);
  }
  const int q = (g >> 6) & 3;
  const int lc = ((g >> 8) << 6) | (g & 63);
#pragma unroll
  for (int r = 0; r < 16; ++r) {
    const int rr = r0 + r;
    const int t = rr >> 7, b = rr & 127;
    Xg[((((size_t)t * 64 + (b >> 1)) * 2 + (b & 1)) * 4 + q) * 256 + lc] = acc[r];
  }
}

// ---------------------------------------------------------------------------
// zero flags with AGENT-scope atomic stores (coherence-point visible)
// ---------------------------------------------------------------------------
__global__ void zero_flags(float* __restrict__ ws) {
  const int i = blockIdx.x * 1024 + threadIdx.x;  // [0, 2048)
  __hip_atomic_store(((unsigned*)(ws + OFF_FLAGS)) + i, 0u, __ATOMIC_RELAXED,
                     __HIP_MEMORY_SCOPE_AGENT);
}

// ---------------------------------------------------------------------------
// Sequential recurrence: L2 streaming, 4-WG groups, one barrier per step.
// ---------------------------------------------------------------------------
__global__ void __launch_bounds__(BLK, 2)
seq5(const float* __restrict__ b_ih,
     const float* __restrict__ b_hh,
     const int* __restrict__ ops,
     float* __restrict__ ws,
     float* __restrict__ out) {
  const int q = blockIdx.x >> 6;    // 0..3 (group members share bp -> same XCD)
  const int bp = blockIdx.x & 63;   // 0..63
  const int tid = threadIdx.x;
  const int ks = tid >> 8;          // 0..1  k-half for dot phases
  const int lc = tid & 255;         // col within quarter
  const int g = ((lc >> 6) << 8) + q * 64 + (lc & 63);  // global gate col

  const float* __restrict__ Xg = ws + OFF_XG;
  const unsigned* __restrict__ PW = (const unsigned*)(ws + OFF_PW);
  unsigned* __restrict__ Hx0u = (unsigned*)(ws + OFF_HX0);
  unsigned* __restrict__ Hx1u = (unsigned*)(ws + OFF_HX1);
  unsigned* __restrict__ flagbase = (unsigned*)(ws + OFF_FLAGS) + bp * 32;

  __shared__ unsigned hp0[256];   // [2 b][128 k2] f16 pairs, gated h0
  __shared__ unsigned hp1[256];
  __shared__ unsigned h0c[256];   // raw h0(t), layer-1 input
  __shared__ float part[1024];    // [2 ks][2 b][256 lc]
  __shared__ float gat[512];      // [2 b][256 lc]
  __shared__ int opsL[TT * 2];    // [t][b]

  for (int i = tid; i < TT * 2; i += BLK)
    opsL[i] = ops[(i >> 1) * BB + bp * 2 + (i & 1)];
  for (int i = tid; i < 256; i += BLK) { hp0[i] = 0u; hp1[i] = 0u; }

  const float bias0 = b_hh[g];                         // b_ih0 folded into Xg
  const float bias1 = b_ih[G4 + g] + b_hh[G4 + g];
  // thread's weight-column base pointers (stride-1024 rows)
  const unsigned* wc0 = PW + (size_t)(ks * 64) * 1024 + g;            // W_hh0
  const unsigned* wc1 = PW + 131072 + (size_t)(ks * 64) * 1024 + g;   // W_ih1
  const unsigned* wc2 = PW + 262144 + (size_t)(ks * 64) * 1024 + g;   // W_hh1

  float cp0 = 0.f, cp1 = 0.f;              // cell state (tid<128)
  const int cb = tid >> 6, ch = tid & 63;  // cell thread mapping
  __syncthreads();

  for (int t = 0; t < TT; ++t) {
    const int par = t & 1;
    // reducer-identity Xg prefetch (b = tid>>8, lc = tid&255)
    const float xgv =
        Xg[((((size_t)t * 64 + bp) * 2 + (tid >> 8)) * 4 + q) * 256 + (tid & 255)];

    // ---- phase A: layer-0 dots (W_hh0 . hp0) for both b ----
    {
      float a0 = 0.f, a1 = 0.f;
      dots64(wc0, hp0 + ks * 64, hp0 + 128 + ks * 64, a0, a1);
      part[(ks * 2 + 0) * 256 + lc] = a0;
      part[(ks * 2 + 1) * 256 + lc] = a1;
    }
    __syncthreads();
    // ---- reduce0: gat[b][lc] ----
    {
      const int rb = tid >> 8, rl = tid & 255;
      gat[rb * 256 + rl] = part[rb * 256 + rl] + part[(2 + rb) * 256 + rl] +
                           bias0 + xgv;
    }
    __syncthreads();
    // ---- cell 0: compute h0, publish f16 directly to Hx0 ----
    if (tid < 128) {
      const float ig = gat[cb * 256 + ch],       fg = gat[cb * 256 + 64 + ch];
      const float gg = gat[cb * 256 + 128 + ch], og = gat[cb * 256 + 192 + ch];
      const float c = sigf(fg) * cp0 + sigf(ig) * tanhf(gg);
      const float h = sigf(og) * tanhf(c);
      if (opsL[t * 2 + cb]) cp0 = c;
      ((unsigned short*)Hx0u)[((par * 64 + bp) * 2 + cb) * 256 + q * 64 + ch] =
          __half_as_ushort(__float2half(h));
    }
    __syncthreads();  // drain cell-0 global stores (vmcnt) before flag

    // ---- group barrier: release-store my flag, acquire-poll all 4 ----
    if (tid == 0)
      __hip_atomic_store(flagbase + q, (unsigned)(t + 1), __ATOMIC_RELEASE,
                         __HIP_MEMORY_SCOPE_AGENT);
    if (tid < 64) {
      const unsigned tgt = (unsigned)(t + 1);
      int spins = 0;
      for (;;) {
        const unsigned v = __hip_atomic_load(flagbase + (tid & 3), __ATOMIC_ACQUIRE,
                                             __HIP_MEMORY_SCOPE_AGENT);
        if (__all((int)(v >= tgt))) break;
        __builtin_amdgcn_s_sleep(1);
        if (++spins > (1 << 22)) break;  // fail loudly instead of hanging
      }
    }
    __syncthreads();

    // ---- merge published h0(t) and h1(t-1) ----
    if (tid < 256) {
      const int b = tid >> 7, k2 = tid & 127;
      const unsigned v = Hx0u[((par * 64 + bp) * 2 + b) * 128 + k2];
      h0c[b * 128 + k2] = v;
      if (opsL[t * 2 + b]) hp0[b * 128 + k2] = v;
    } else if (t > 0) {
      const int i2 = tid - 256;
      const int b = i2 >> 7, k2 = i2 & 127;
      const unsigned v = Hx1u[(((par ^ 1) * 64 + bp) * 2 + b) * 128 + k2];
      if (opsL[(t - 1) * 2 + b]) hp1[b * 128 + k2] = v;
    }
    __syncthreads();

    // ---- phase B: layer-1 dots (W_ih1 . h0c + W_hh1 . hp1) ----
    {
      float a0 = 0.f, a1 = 0.f;
      dots64(wc1, h0c + ks * 64, h0c + 128 + ks * 64, a0, a1);
      dots64(wc2, hp1 + ks * 64, hp1 + 128 + ks * 64, a0, a1);
      part[(ks * 2 + 0) * 256 + lc] = a0;
      part[(ks * 2 + 1) * 256 + lc] = a1;
    }
    __syncthreads();
    // ---- reduce1 ----
    {
      const int rb = tid >> 8, rl = tid & 255;
      gat[rb * 256 + rl] = part[rb * 256 + rl] + part[(2 + rb) * 256 + rl] + bias1;
    }
    __syncthreads();
    // ---- cell 1: output + publish h1 ----
    if (tid < 128) {
      const float ig = gat[cb * 256 + ch],       fg = gat[cb * 256 + 64 + ch];
      const float gg = gat[cb * 256 + 128 + ch], og = gat[cb * 256 + 192 + ch];
      const float c = sigf(fg) * cp1 + sigf(ig) * tanhf(gg);
      const float h = sigf(og) * tanhf(c);
      if (opsL[t * 2 + cb]) cp1 = c;
      out[((size_t)t * BB + bp * 2 + cb) * HH + q * 64 + ch] = h;
      ((unsigned short*)Hx1u)[((par * 64 + bp) * 2 + cb) * 256 + q * 64 + ch] =
          __half_as_ushort(__float2half(h));
    }
    __syncthreads();  // h1 stores drained at next barrier chain; part safety
  }
}

// ---------------------------------------------------------------------------
extern "C" void kernel_launch(void* const* d_in, const int* in_sizes, int n_in,
                              void* d_out, int out_size, void* d_ws, size_t ws_size,
                              hipStream_t stream) {
  const float* x    = (const float*)d_in[0];
  const int*   ops  = (const int*)d_in[1];
  const float* W_ih = (const float*)d_in[2];
  const float* W_hh = (const float*)d_in[3];
  const float* b_ih = (const float*)d_in[4];
  const float* b_hh = (const float*)d_in[5];
  float* out = (float*)d_out;
  float* ws  = (float*)d_ws;

  transpose1<<<dim3(32, 8), dim3(32, 8), 0, stream>>>(W_ih, ws);
  pack_f16<<<1536, 256, 0, stream>>>(W_ih, W_hh, ws);
  xg_kernel<<<dim3(512, 4), 256, 0, stream>>>(x, b_ih, ws);
  zero_flags<<<2, 1024, 0, stream>>>(ws);
  seq5<<<256, BLK, 0, stream>>>(b_ih, b_hh, ops, ws, out);
}

// Round 6
// 2287.320 us; speedup vs baseline: 1.4845x; 1.4845x over previous
//
#include <hip/hip_runtime.h>
#include <hip/hip_fp16.h>
#include <cstddef>

// StackLSTM: T=64, B=128, H=256, L=2.  ops∈{0,1} => stack never pops:
// top-of-stack = h(last push step), maintained by gated update.
//
// Round-6: persistent-RNN style. 512 WGs = (bg 0..31 x hg 0..15); WG owns
// 4 batch elems x 16 h-cols (64 gate cols/layer). Each thread (c2,kq) holds
// its weight slice (96 packed-f16 uints) in VGPRs for the whole kernel ->
// zero weight traffic in the hot loop. h vectors in LDS; k-reduction via
// __shfl_xor over the 8 kq lanes. One flag barrier per step (16 WGs/group,
// XCD-local by construction), signed flags (0xAA poison = negative, no
// zeroing needed), 16-lane acquire poll with s_sleep throttle (no storm).
#define TT 64
#define BB 128
#define HH 256
#define G4 1024
#define BLK 256
#define NBG 32
#define NHG 16

// ws float-slot offsets
#define OFF_XG     0u          // [64 t][16 hg][128 b][64 lc] fp32 = 8,388,608
#define OFF_WTIH0  8388608u    // [256][1024] fp32 W_ih[0]^T (for xg) = 262,144
#define OFF_HX0    8650752u    // uint [2 par][32 bg][4 b][128 k2] = 32,768
#define OFF_HX1    8683520u    // same
#define OFF_FLAGS  8716288u    // int [32 bg][16 hg] = 512 (64 B per group)
// total 8,716,800 floats = 34.9 MB

__device__ __forceinline__ float sigf(float x) { return 1.0f / (1.0f + expf(-x)); }

typedef _Float16 h2v __attribute__((ext_vector_type(2)));

__device__ __forceinline__ float dot2acc(unsigned w, unsigned h, float acc) {
#if __has_builtin(__builtin_amdgcn_fdot2)
  return __builtin_amdgcn_fdot2(__builtin_bit_cast(h2v, w),
                                __builtin_bit_cast(h2v, h), acc, false);
#else
  __half2 wv = *(__half2*)&w, hv = *(__half2*)&h;
  float2 wf = __half22float2(wv), hf = __half22float2(hv);
  return fmaf(wf.x, hf.x, fmaf(wf.y, hf.y, acc));
#endif
}

__device__ __forceinline__ unsigned packh2(float e, float o) {
  return (unsigned)__half_as_ushort(__float2half(e)) |
         ((unsigned)__half_as_ushort(__float2half(o)) << 16);
}

// ---------------------------------------------------------------------------
// transpose W_ih[0] [1024][256] -> [256][1024] fp32 (for xg_kernel)
// ---------------------------------------------------------------------------
__global__ void transpose1(const float* __restrict__ W_ih, float* __restrict__ ws) {
  __shared__ float tile[32][33];
  float* dst = ws + OFF_WTIH0;
  const int g0 = blockIdx.x * 32, k0 = blockIdx.y * 32;
  const int tx = threadIdx.x, ty = threadIdx.y;
#pragma unroll
  for (int i = 0; i < 32; i += 8)
    tile[ty + i][tx] = W_ih[(size_t)(g0 + ty + i) * HH + k0 + tx];
  __syncthreads();
#pragma unroll
  for (int i = 0; i < 32; i += 8)
    dst[(size_t)(k0 + ty + i) * G4 + g0 + tx] = tile[tx][ty + i];
}

// ---------------------------------------------------------------------------
// Xg[t][hg][b][lc] = b_ih0[g] + x[t,b,:] @ W_ih0[g,:]   (fp32, exact)
// g = (lc>>4)*256 + hg*16 + (lc&15)
// ---------------------------------------------------------------------------
__global__ void xg_kernel(const float* __restrict__ x,
                          const float* __restrict__ b_ih,
                          float* __restrict__ ws) {
  const float* __restrict__ WTih0 = ws + OFF_WTIH0;
  float* __restrict__ Xg = ws + OFF_XG;
  const int r0 = blockIdx.x * 16;
  const int g = blockIdx.y * 256 + threadIdx.x;
  __shared__ float xs[16][HH];
  for (int i = threadIdx.x; i < 16 * HH; i += 256)
    xs[i >> 8][i & 255] = x[(size_t)(r0 + (i >> 8)) * HH + (i & 255)];
  __syncthreads();
  float acc[16];
  const float bias = b_ih[g];
#pragma unroll
  for (int r = 0; r < 16; ++r) acc[r] = bias;
  for (int k = 0; k < HH; ++k) {
    const float w = WTih0[(size_t)k * G4 + g];
#pragma unroll
    for (int r = 0; r < 16; ++r) acc[r] = fmaf(xs[r][k], w, acc[r]);
  }
  const int hg = (g >> 4) & 15;
  const int lc = ((g >> 8) << 4) | (g & 15);
#pragma unroll
  for (int r = 0; r < 16; ++r) {
    const int rr = r0 + r;
    const int t = rr >> 7, b = rr & 127;
    Xg[(((size_t)t * NHG + hg) * 128 + b) * 64 + lc] = acc[r];
  }
}

// ---------------------------------------------------------------------------
// Sequential recurrence, register-resident weights.
// ---------------------------------------------------------------------------
__global__ void __launch_bounds__(BLK, 2)
seq6(const float* __restrict__ W_ih,
     const float* __restrict__ W_hh,
     const float* __restrict__ b_ih,
     const float* __restrict__ b_hh,
     const int* __restrict__ ops,
     float* __restrict__ ws,
     float* __restrict__ out) {
  const int bg = blockIdx.x & 31;     // batch group (4 b)
  const int hg = blockIdx.x >> 5;     // 0..15 (group members: same bg -> same XCD)
  const int tid = threadIdx.x;
  const int kq = tid & 7;             // k-slice: k2 in [kq*16, kq*16+16)
  const int c2 = tid >> 3;            // 0..31: cols {c2*2, c2*2+1}

  __shared__ float XgL[TT * 256];     // 64 KB [t][b][lc]
  __shared__ unsigned hp0[512];       // [4 b][128 k2] f16-pair gated h0
  __shared__ unsigned hp1[512];
  __shared__ unsigned h0c[512];       // raw h0(t), layer-1 input
  __shared__ float gat[256];          // [4 b][64 lc]
  __shared__ int opsA[TT * 4];        // [t][b]

  // ---- prologue: weights -> VGPRs (f16 pairs), Xg slice -> LDS ----
  unsigned wr0[32], wr1[32], wr2[32];
  {
    const float* s0 = W_hh;                       // W_hh[0]
    const float* s1 = W_ih + (size_t)G4 * HH;     // W_ih[1]
    const float* s2 = W_hh + (size_t)G4 * HH;     // W_hh[1]
#pragma unroll
    for (int j = 0; j < 2; ++j) {
      const int lc = c2 * 2 + j;
      const int g = ((lc >> 4) << 8) + hg * 16 + (lc & 15);
      const float* p0 = s0 + (size_t)g * HH + kq * 32;
      const float* p1 = s1 + (size_t)g * HH + kq * 32;
      const float* p2 = s2 + (size_t)g * HH + kq * 32;
#pragma unroll
      for (int i = 0; i < 16; ++i) {
        wr0[j * 16 + i] = packh2(p0[2 * i], p0[2 * i + 1]);
        wr1[j * 16 + i] = packh2(p1[2 * i], p1[2 * i + 1]);
        wr2[j * 16 + i] = packh2(p2[2 * i], p2[2 * i + 1]);
      }
    }
  }
  float bias0r[2], bias1r[2];
#pragma unroll
  for (int j = 0; j < 2; ++j) {
    const int lc = c2 * 2 + j;
    const int g = ((lc >> 4) << 8) + hg * 16 + (lc & 15);
    bias0r[j] = b_hh[g];                           // b_ih0 folded into Xg
    bias1r[j] = b_ih[G4 + g] + b_hh[G4 + g];
  }
  for (int i = tid; i < TT * 64; i += BLK) {       // 4096 float4
    const int t = i >> 6, r = i & 63;
    ((float4*)XgL)[i] = *(const float4*)(
        ws + OFF_XG + (((size_t)t * NHG + hg) * 128 + bg * 4) * 64 + r * 4);
  }
  for (int i = tid; i < TT * 4; i += BLK)
    opsA[i] = ops[(i >> 2) * BB + bg * 4 + (i & 3)];
  for (int i = tid; i < 512; i += BLK) { hp0[i] = 0u; hp1[i] = 0u; }

  unsigned* __restrict__ Hx0u = (unsigned*)(ws + OFF_HX0);
  unsigned* __restrict__ Hx1u = (unsigned*)(ws + OFF_HX1);
  int* __restrict__ flagp = (int*)(ws + OFF_FLAGS) + bg * 16;
  float cp0 = 0.f, cp1 = 0.f;         // cell state, held by tid<64
  __syncthreads();

  for (int t = 0; t < TT; ++t) {
    const int par = t & 1;

    // ---- layer-0 dots: wr0 . hp0 (weights in regs, h in LDS) ----
    float a0[4][2];
#pragma unroll
    for (int b = 0; b < 4; ++b) {
      const uint4 x0 = *(const uint4*)&hp0[b * 128 + kq * 16];
      const uint4 x1 = *(const uint4*)&hp0[b * 128 + kq * 16 + 4];
      const uint4 x2 = *(const uint4*)&hp0[b * 128 + kq * 16 + 8];
      const uint4 x3 = *(const uint4*)&hp0[b * 128 + kq * 16 + 12];
      const unsigned hh[16] = {x0.x, x0.y, x0.z, x0.w, x1.x, x1.y, x1.z, x1.w,
                               x2.x, x2.y, x2.z, x2.w, x3.x, x3.y, x3.z, x3.w};
#pragma unroll
      for (int j = 0; j < 2; ++j) {
        float a = 0.f;
#pragma unroll
        for (int i = 0; i < 16; ++i) a = dot2acc(wr0[j * 16 + i], hh[i], a);
        a0[b][j] = a;
      }
    }
#pragma unroll
    for (int m = 1; m <= 4; m <<= 1)
#pragma unroll
      for (int b = 0; b < 4; ++b) {
        a0[b][0] += __shfl_xor(a0[b][0], m, 64);
        a0[b][1] += __shfl_xor(a0[b][1], m, 64);
      }
    if (kq == 0) {
#pragma unroll
      for (int b = 0; b < 4; ++b)
        *(float2*)&gat[b * 64 + c2 * 2] =
            make_float2(a0[b][0] + bias0r[0], a0[b][1] + bias0r[1]);
    }
    __syncthreads();

    // ---- cell 0 + publish h0 (f16 shorts) ----
    if (tid < 64) {
      const int b = tid >> 4, r = tid & 15;
      const float* xg = &XgL[t * 256 + b * 64];
      const float* gt = &gat[b * 64];
      const float ig = gt[r] + xg[r],           fg = gt[16 + r] + xg[16 + r];
      const float gg = gt[32 + r] + xg[32 + r], og = gt[48 + r] + xg[48 + r];
      const float c = sigf(fg) * cp0 + sigf(ig) * tanhf(gg);
      const float h = sigf(og) * tanhf(c);
      if (opsA[t * 4 + b]) cp0 = c;
      ((unsigned short*)Hx0u)[((par * NBG + bg) * 4 + b) * 256 + hg * 16 + r] =
          __half_as_ushort(__float2half(h));
    }
    __syncthreads();  // drains vmcnt: publishes complete before flag store

    // ---- flag barrier (signed; 0xAA poison is negative => replay-safe) ----
    if (tid == 0)
      __hip_atomic_store(flagp + hg, t + 1, __ATOMIC_RELEASE,
                         __HIP_MEMORY_SCOPE_AGENT);
    if (tid < 16) {
      int spins = 0;
      while (__hip_atomic_load(flagp + tid, __ATOMIC_ACQUIRE,
                               __HIP_MEMORY_SCOPE_AGENT) < t + 1) {
        __builtin_amdgcn_s_sleep(8);
        if (++spins > (1 << 14)) break;  // fail loudly instead of hanging
      }
    }
    __syncthreads();
    __builtin_amdgcn_fence(__ATOMIC_ACQUIRE, "agent");  // all waves: L1 inv

    // ---- merge h0(t) and h1(t-1) ----
    {
      const unsigned* s0 = Hx0u + (par * NBG + bg) * 512;
      const uint2 v = *(const uint2*)(s0 + 2 * tid);
      const int b = tid >> 6;
      h0c[2 * tid] = v.x; h0c[2 * tid + 1] = v.y;
      if (opsA[t * 4 + b]) { hp0[2 * tid] = v.x; hp0[2 * tid + 1] = v.y; }
      if (t > 0) {
        const unsigned* s1 = Hx1u + ((par ^ 1) * NBG + bg) * 512;
        const uint2 w = *(const uint2*)(s1 + 2 * tid);
        if (opsA[(t - 1) * 4 + b]) { hp1[2 * tid] = w.x; hp1[2 * tid + 1] = w.y; }
      }
    }
    __syncthreads();

    // ---- layer-1 dots: wr1 . h0c + wr2 . hp1 ----
    float a1[4][2];
#pragma unroll
    for (int b = 0; b < 4; ++b) {
      const uint4 c0 = *(const uint4*)&h0c[b * 128 + kq * 16];
      const uint4 c1 = *(const uint4*)&h0c[b * 128 + kq * 16 + 4];
      const uint4 c2v = *(const uint4*)&h0c[b * 128 + kq * 16 + 8];
      const uint4 c3 = *(const uint4*)&h0c[b * 128 + kq * 16 + 12];
      const uint4 q0 = *(const uint4*)&hp1[b * 128 + kq * 16];
      const uint4 q1 = *(const uint4*)&hp1[b * 128 + kq * 16 + 4];
      const uint4 q2 = *(const uint4*)&hp1[b * 128 + kq * 16 + 8];
      const uint4 q3 = *(const uint4*)&hp1[b * 128 + kq * 16 + 12];
      const unsigned hc[16] = {c0.x, c0.y, c0.z, c0.w, c1.x, c1.y, c1.z, c1.w,
                               c2v.x, c2v.y, c2v.z, c2v.w, c3.x, c3.y, c3.z, c3.w};
      const unsigned hq[16] = {q0.x, q0.y, q0.z, q0.w, q1.x, q1.y, q1.z, q1.w,
                               q2.x, q2.y, q2.z, q2.w, q3.x, q3.y, q3.z, q3.w};
#pragma unroll
      for (int j = 0; j < 2; ++j) {
        float a = 0.f;
#pragma unroll
        for (int i = 0; i < 16; ++i) {
          a = dot2acc(wr1[j * 16 + i], hc[i], a);
          a = dot2acc(wr2[j * 16 + i], hq[i], a);
        }
        a1[b][j] = a;
      }
    }
#pragma unroll
    for (int m = 1; m <= 4; m <<= 1)
#pragma unroll
      for (int b = 0; b < 4; ++b) {
        a1[b][0] += __shfl_xor(a1[b][0], m, 64);
        a1[b][1] += __shfl_xor(a1[b][1], m, 64);
      }
    if (kq == 0) {
#pragma unroll
      for (int b = 0; b < 4; ++b)
        *(float2*)&gat[b * 64 + c2 * 2] =
            make_float2(a1[b][0] + bias1r[0], a1[b][1] + bias1r[1]);
    }
    __syncthreads();

    // ---- cell 1: output + publish h1 ----
    if (tid < 64) {
      const int b = tid >> 4, r = tid & 15;
      const float* gt = &gat[b * 64];
      const float ig = gt[r],      fg = gt[16 + r];
      const float gg = gt[32 + r], og = gt[48 + r];
      const float c = sigf(fg) * cp1 + sigf(ig) * tanhf(gg);
      const float h = sigf(og) * tanhf(c);
      if (opsA[t * 4 + b]) cp1 = c;
      out[((size_t)t * BB + bg * 4 + b) * HH + hg * 16 + r] = h;
      ((unsigned short*)Hx1u)[((par * NBG + bg) * 4 + b) * 256 + hg * 16 + r] =
          __half_as_ushort(__float2half(h));
    }
    __syncthreads();  // gat/hp reuse safety for next step
  }
}

// ---------------------------------------------------------------------------
extern "C" void kernel_launch(void* const* d_in, const int* in_sizes, int n_in,
                              void* d_out, int out_size, void* d_ws, size_t ws_size,
                              hipStream_t stream) {
  const float* x    = (const float*)d_in[0];
  const int*   ops  = (const int*)d_in[1];
  const float* W_ih = (const float*)d_in[2];
  const float* W_hh = (const float*)d_in[3];
  const float* b_ih = (const float*)d_in[4];
  const float* b_hh = (const float*)d_in[5];
  float* out = (float*)d_out;
  float* ws  = (float*)d_ws;

  transpose1<<<dim3(32, 8), dim3(32, 8), 0, stream>>>(W_ih, ws);
  xg_kernel<<<dim3(512, 4), 256, 0, stream>>>(x, b_ih, ws);
  seq6<<<512, BLK, 0, stream>>>(W_ih, W_hh, b_ih, b_hh, ops, ws, out);
}

// Round 7
// 561.192 us; speedup vs baseline: 6.0506x; 4.0758x over previous
//
#include <hip/hip_runtime.h>
#include <hip/hip_fp16.h>
#include <cstddef>

// StackLSTM: T=64, B=128, H=256, L=2.  ops∈{0,1} => stack never pops:
// top-of-stack = h(last push step), maintained by gated update.
//
// Round-7: register-resident weights (as r6) + FENCE-FREE tagged dataflow
// exchange: h published as 8-B relaxed agent atomics {tag=t+1, f16x2}; readers
// poll the exact words they need. No release/acquire, no buffer_inv, no flags.
#define TT 64
#define BB 128
#define HH 256
#define G4 1024
#define BLK 256
#define NBG 32
#define NHG 16

// ws float-slot offsets
#define OFF_XG     0u          // [64 t][16 hg][128 b][64 lc] fp32 = 8,388,608
#define OFF_WTIH0  8388608u    // [256][1024] fp32 W_ih[0]^T (for xg) = 262,144
#define OFF_HX0    8650752u    // u64 [2 par][32 bg][4 b][128 k2] = 65,536 floats
#define OFF_HX1    8716288u    // same
// total 8,781,824 floats = 35.1 MB

__device__ __forceinline__ float sigf(float x) { return 1.0f / (1.0f + expf(-x)); }

typedef _Float16 h2v __attribute__((ext_vector_type(2)));

__device__ __forceinline__ float dot2acc(unsigned w, unsigned h, float acc) {
#if __has_builtin(__builtin_amdgcn_fdot2)
  return __builtin_amdgcn_fdot2(__builtin_bit_cast(h2v, w),
                                __builtin_bit_cast(h2v, h), acc, false);
#else
  __half2 wv = *(__half2*)&w, hv = *(__half2*)&h;
  float2 wf = __half22float2(wv), hf = __half22float2(hv);
  return fmaf(wf.x, hf.x, fmaf(wf.y, hf.y, acc));
#endif
}

__device__ __forceinline__ unsigned packh2(float e, float o) {
  return (unsigned)__half_as_ushort(__float2half(e)) |
         ((unsigned)__half_as_ushort(__float2half(o)) << 16);
}

// ---------------------------------------------------------------------------
// transpose W_ih[0] [1024][256] -> [256][1024] fp32 (for xg_kernel)
// ---------------------------------------------------------------------------
__global__ void transpose1(const float* __restrict__ W_ih, float* __restrict__ ws) {
  __shared__ float tile[32][33];
  float* dst = ws + OFF_WTIH0;
  const int g0 = blockIdx.x * 32, k0 = blockIdx.y * 32;
  const int tx = threadIdx.x, ty = threadIdx.y;
#pragma unroll
  for (int i = 0; i < 32; i += 8)
    tile[ty + i][tx] = W_ih[(size_t)(g0 + ty + i) * HH + k0 + tx];
  __syncthreads();
#pragma unroll
  for (int i = 0; i < 32; i += 8)
    dst[(size_t)(k0 + ty + i) * G4 + g0 + tx] = tile[tx][ty + i];
}

// ---------------------------------------------------------------------------
// Xg[t][hg][b][lc] = b_ih0[g] + x[t,b,:] @ W_ih0[g,:]   (fp32, exact)
// g = (lc>>4)*256 + hg*16 + (lc&15)
// ---------------------------------------------------------------------------
__global__ void xg_kernel(const float* __restrict__ x,
                          const float* __restrict__ b_ih,
                          float* __restrict__ ws) {
  const float* __restrict__ WTih0 = ws + OFF_WTIH0;
  float* __restrict__ Xg = ws + OFF_XG;
  const int r0 = blockIdx.x * 16;
  const int g = blockIdx.y * 256 + threadIdx.x;
  __shared__ float xs[16][HH];
  for (int i = threadIdx.x; i < 16 * HH; i += 256)
    xs[i >> 8][i & 255] = x[(size_t)(r0 + (i >> 8)) * HH + (i & 255)];
  __syncthreads();
  float acc[16];
  const float bias = b_ih[g];
#pragma unroll
  for (int r = 0; r < 16; ++r) acc[r] = bias;
  for (int k = 0; k < HH; ++k) {
    const float w = WTih0[(size_t)k * G4 + g];
#pragma unroll
    for (int r = 0; r < 16; ++r) acc[r] = fmaf(xs[r][k], w, acc[r]);
  }
  const int hg = (g >> 4) & 15;
  const int lc = ((g >> 8) << 4) | (g & 15);
#pragma unroll
  for (int r = 0; r < 16; ++r) {
    const int rr = r0 + r;
    const int t = rr >> 7, b = rr & 127;
    Xg[(((size_t)t * NHG + hg) * 128 + b) * 64 + lc] = acc[r];
  }
}

// ---------------------------------------------------------------------------
// Sequential recurrence: register weights + tagged dataflow exchange.
// ---------------------------------------------------------------------------
__global__ void __launch_bounds__(BLK, 2)
seq7(const float* __restrict__ W_ih,
     const float* __restrict__ W_hh,
     const float* __restrict__ b_ih,
     const float* __restrict__ b_hh,
     const int* __restrict__ ops,
     float* __restrict__ ws,
     float* __restrict__ out) {
  const int bg = blockIdx.x & 31;     // batch group (4 b); group = same bg
  const int hg = blockIdx.x >> 5;     // 0..15
  const int tid = threadIdx.x;
  const int kq = tid & 7;             // k-slice: k2 in [kq*16, kq*16+16)
  const int c2 = tid >> 3;            // 0..31: cols {c2*2, c2*2+1}

  __shared__ float XgL[TT * 256];     // 64 KB [t][b][lc]
  __shared__ unsigned hp0[512];       // [4 b][128 k2] f16-pair gated h0
  __shared__ unsigned hp1[512];
  __shared__ unsigned h0c[512];       // raw h0(t), layer-1 input
  __shared__ float gat[256];          // [4 b][64 lc]
  __shared__ int opsA[TT * 4];        // [t][b]

  // ---- prologue: weights -> VGPRs (f16 pairs), Xg slice -> LDS ----
  unsigned wr0[32], wr1[32], wr2[32];
  {
    const float* s0 = W_hh;                       // W_hh[0]
    const float* s1 = W_ih + (size_t)G4 * HH;     // W_ih[1]
    const float* s2 = W_hh + (size_t)G4 * HH;     // W_hh[1]
#pragma unroll
    for (int j = 0; j < 2; ++j) {
      const int lc = c2 * 2 + j;
      const int g = ((lc >> 4) << 8) + hg * 16 + (lc & 15);
      const float* p0 = s0 + (size_t)g * HH + kq * 32;
      const float* p1 = s1 + (size_t)g * HH + kq * 32;
      const float* p2 = s2 + (size_t)g * HH + kq * 32;
#pragma unroll
      for (int i = 0; i < 16; ++i) {
        wr0[j * 16 + i] = packh2(p0[2 * i], p0[2 * i + 1]);
        wr1[j * 16 + i] = packh2(p1[2 * i], p1[2 * i + 1]);
        wr2[j * 16 + i] = packh2(p2[2 * i], p2[2 * i + 1]);
      }
    }
  }
  float bias0r[2], bias1r[2];
#pragma unroll
  for (int j = 0; j < 2; ++j) {
    const int lc = c2 * 2 + j;
    const int g = ((lc >> 4) << 8) + hg * 16 + (lc & 15);
    bias0r[j] = b_hh[g];                           // b_ih0 folded into Xg
    bias1r[j] = b_ih[G4 + g] + b_hh[G4 + g];
  }
  for (int i = tid; i < TT * 64; i += BLK) {       // 4096 float4
    const int t = i >> 6, r = i & 63;
    ((float4*)XgL)[i] = *(const float4*)(
        ws + OFF_XG + (((size_t)t * NHG + hg) * 128 + bg * 4) * 64 + r * 4);
  }
  for (int i = tid; i < TT * 4; i += BLK)
    opsA[i] = ops[(i >> 2) * BB + bg * 4 + (i & 3)];
  for (int i = tid; i < 512; i += BLK) { hp0[i] = 0u; hp1[i] = 0u; }

  unsigned long long* __restrict__ Hx0 = (unsigned long long*)(ws + OFF_HX0);
  unsigned long long* __restrict__ Hx1 = (unsigned long long*)(ws + OFF_HX1);
  float cp0 = 0.f, cp1 = 0.f;         // cell state, held by tid<64
  __syncthreads();

  for (int t = 0; t < TT; ++t) {
    const int par = t & 1;

    // ---- layer-0 dots: wr0 . hp0 (weights in regs, h in LDS) ----
    float a0[4][2];
#pragma unroll
    for (int b = 0; b < 4; ++b) {
      const uint4 x0 = *(const uint4*)&hp0[b * 128 + kq * 16];
      const uint4 x1 = *(const uint4*)&hp0[b * 128 + kq * 16 + 4];
      const uint4 x2 = *(const uint4*)&hp0[b * 128 + kq * 16 + 8];
      const uint4 x3 = *(const uint4*)&hp0[b * 128 + kq * 16 + 12];
      const unsigned hh[16] = {x0.x, x0.y, x0.z, x0.w, x1.x, x1.y, x1.z, x1.w,
                               x2.x, x2.y, x2.z, x2.w, x3.x, x3.y, x3.z, x3.w};
#pragma unroll
      for (int j = 0; j < 2; ++j) {
        float a = 0.f;
#pragma unroll
        for (int i = 0; i < 16; ++i) a = dot2acc(wr0[j * 16 + i], hh[i], a);
        a0[b][j] = a;
      }
    }
#pragma unroll
    for (int m = 1; m <= 4; m <<= 1)
#pragma unroll
      for (int b = 0; b < 4; ++b) {
        a0[b][0] += __shfl_xor(a0[b][0], m, 64);
        a0[b][1] += __shfl_xor(a0[b][1], m, 64);
      }
    if (kq == 0) {
#pragma unroll
      for (int b = 0; b < 4; ++b)
        *(float2*)&gat[b * 64 + c2 * 2] =
            make_float2(a0[b][0] + bias0r[0], a0[b][1] + bias0r[1]);
    }
    __syncthreads();

    // ---- cell 0 + tagged publish of h0 (8-B relaxed atomics) ----
    if (tid < 64) {
      const int b = tid >> 4, r = tid & 15;
      const float* xg = &XgL[t * 256 + b * 64];
      const float* gt = &gat[b * 64];
      const float ig = gt[r] + xg[r],           fg = gt[16 + r] + xg[16 + r];
      const float gg = gt[32 + r] + xg[32 + r], og = gt[48 + r] + xg[48 + r];
      const float c = sigf(fg) * cp0 + sigf(ig) * tanhf(gg);
      const float h = sigf(og) * tanhf(c);
      if (opsA[t * 4 + b]) cp0 = c;
      const float ho = __shfl_xor(h, 1, 64);  // pair partner (wave 0 full)
      if (!(r & 1)) {
        const unsigned long long v =
            (unsigned long long)(unsigned)(t + 1) |
            ((unsigned long long)packh2(h, ho) << 32);
        __hip_atomic_store(
            Hx0 + ((size_t)par * NBG + bg) * 512 + b * 128 + hg * 8 + (r >> 1),
            v, __ATOMIC_RELAXED, __HIP_MEMORY_SCOPE_AGENT);
      }
    }
    // no sync: merge polls below self-synchronize on the tags

    // ---- merge: poll tagged words for h0(t) and h1(t-1) ----
    {
      const unsigned long long* s0 = Hx0 + ((size_t)par * NBG + bg) * 512;
      const unsigned tagA = (unsigned)(t + 1);
#pragma unroll
      for (int i = 0; i < 2; ++i) {
        const int idx = tid + i * 256;
        const int b = idx >> 7, k2 = idx & 127;
        unsigned long long v;
        int spins = 0;
        for (;;) {
          v = __hip_atomic_load(s0 + idx, __ATOMIC_RELAXED,
                                __HIP_MEMORY_SCOPE_AGENT);
          if ((unsigned)v == tagA) break;
          if (++spins > (1 << 18)) break;  // fail loudly instead of hanging
          __builtin_amdgcn_s_sleep(1);
        }
        const unsigned pay = (unsigned)(v >> 32);
        h0c[b * 128 + k2] = pay;
        if (opsA[t * 4 + b]) hp0[b * 128 + k2] = pay;
      }
      if (t > 0) {
        const unsigned long long* s1 = Hx1 + ((size_t)(par ^ 1) * NBG + bg) * 512;
        const unsigned tagB = (unsigned)t;
#pragma unroll
        for (int i = 0; i < 2; ++i) {
          const int idx = tid + i * 256;
          const int b = idx >> 7, k2 = idx & 127;
          unsigned long long v;
          int spins = 0;
          for (;;) {
            v = __hip_atomic_load(s1 + idx, __ATOMIC_RELAXED,
                                  __HIP_MEMORY_SCOPE_AGENT);
            if ((unsigned)v == tagB) break;
            if (++spins > (1 << 18)) break;
            __builtin_amdgcn_s_sleep(1);
          }
          if (opsA[(t - 1) * 4 + b]) hp1[b * 128 + k2] = (unsigned)(v >> 32);
        }
      }
    }
    __syncthreads();

    // ---- layer-1 dots: wr1 . h0c + wr2 . hp1 ----
    float a1[4][2];
#pragma unroll
    for (int b = 0; b < 4; ++b) {
      const uint4 c0 = *(const uint4*)&h0c[b * 128 + kq * 16];
      const uint4 c1 = *(const uint4*)&h0c[b * 128 + kq * 16 + 4];
      const uint4 c2v = *(const uint4*)&h0c[b * 128 + kq * 16 + 8];
      const uint4 c3 = *(const uint4*)&h0c[b * 128 + kq * 16 + 12];
      const uint4 q0 = *(const uint4*)&hp1[b * 128 + kq * 16];
      const uint4 q1 = *(const uint4*)&hp1[b * 128 + kq * 16 + 4];
      const uint4 q2 = *(const uint4*)&hp1[b * 128 + kq * 16 + 8];
      const uint4 q3 = *(const uint4*)&hp1[b * 128 + kq * 16 + 12];
      const unsigned hc[16] = {c0.x, c0.y, c0.z, c0.w, c1.x, c1.y, c1.z, c1.w,
                               c2v.x, c2v.y, c2v.z, c2v.w, c3.x, c3.y, c3.z, c3.w};
      const unsigned hq[16] = {q0.x, q0.y, q0.z, q0.w, q1.x, q1.y, q1.z, q1.w,
                               q2.x, q2.y, q2.z, q2.w, q3.x, q3.y, q3.z, q3.w};
#pragma unroll
      for (int j = 0; j < 2; ++j) {
        float a = 0.f;
#pragma unroll
        for (int i = 0; i < 16; ++i) {
          a = dot2acc(wr1[j * 16 + i], hc[i], a);
          a = dot2acc(wr2[j * 16 + i], hq[i], a);
        }
        a1[b][j] = a;
      }
    }
#pragma unroll
    for (int m = 1; m <= 4; m <<= 1)
#pragma unroll
      for (int b = 0; b < 4; ++b) {
        a1[b][0] += __shfl_xor(a1[b][0], m, 64);
        a1[b][1] += __shfl_xor(a1[b][1], m, 64);
      }
    if (kq == 0) {
#pragma unroll
      for (int b = 0; b < 4; ++b)
        *(float2*)&gat[b * 64 + c2 * 2] =
            make_float2(a1[b][0] + bias1r[0], a1[b][1] + bias1r[1]);
    }
    __syncthreads();

    // ---- cell 1: output + tagged publish of h1 ----
    if (tid < 64) {
      const int b = tid >> 4, r = tid & 15;
      const float* gt = &gat[b * 64];
      const float ig = gt[r],      fg = gt[16 + r];
      const float gg = gt[32 + r], og = gt[48 + r];
      const float c = sigf(fg) * cp1 + sigf(ig) * tanhf(gg);
      const float h = sigf(og) * tanhf(c);
      if (opsA[t * 4 + b]) cp1 = c;
      out[((size_t)t * BB + bg * 4 + b) * HH + hg * 16 + r] = h;
      const float ho = __shfl_xor(h, 1, 64);
      if (!(r & 1)) {
        const unsigned long long v =
            (unsigned long long)(unsigned)(t + 1) |
            ((unsigned long long)packh2(h, ho) << 32);
        __hip_atomic_store(
            Hx1 + ((size_t)par * NBG + bg) * 512 + b * 128 + hg * 8 + (r >> 1),
            v, __ATOMIC_RELAXED, __HIP_MEMORY_SCOPE_AGENT);
      }
    }
    __syncthreads();  // gat reuse safety for next step
  }
}

// ---------------------------------------------------------------------------
extern "C" void kernel_launch(void* const* d_in, const int* in_sizes, int n_in,
                              void* d_out, int out_size, void* d_ws, size_t ws_size,
                              hipStream_t stream) {
  const float* x    = (const float*)d_in[0];
  const int*   ops  = (const int*)d_in[1];
  const float* W_ih = (const float*)d_in[2];
  const float* W_hh = (const float*)d_in[3];
  const float* b_ih = (const float*)d_in[4];
  const float* b_hh = (const float*)d_in[5];
  float* out = (float*)d_out;
  float* ws  = (float*)d_ws;

  transpose1<<<dim3(32, 8), dim3(32, 8), 0, stream>>>(W_ih, ws);
  xg_kernel<<<dim3(512, 4), 256, 0, stream>>>(x, b_ih, ws);
  seq7<<<512, BLK, 0, stream>>>(W_ih, W_hh, b_ih, b_hh, ops, ws, out);
}